// Round 5
// baseline (571.764 us; speedup 1.0000x reference)
//
#include <hip/hip_runtime.h>
#include <cstdint>
#include <cstddef>

namespace {

constexpr int Bb  = 8;
constexpr int Tt  = 1024;
constexpr int Dd  = 768;
constexpr int Hh  = 12;
constexpr int DFF = 3072;
constexpr int BT  = Bb * Tt;

typedef __attribute__((ext_vector_type(8))) short bf16x8;
typedef __attribute__((ext_vector_type(4))) short bf16x4;
typedef __attribute__((ext_vector_type(4))) float f32x4;

__device__ __forceinline__ short f2bf(float f) {
  union { float f; unsigned u; } v; v.f = f;
  unsigned r = v.u + 0x7fffu + ((v.u >> 16) & 1u);   // RNE
  return (short)(r >> 16);
}
__device__ __forceinline__ float gelu_exact(float v) {
  return 0.5f * v * (1.0f + erff(v * 0.70710678118654752f));
}

#define MFMA16(a, b, c) __builtin_amdgcn_mfma_f32_16x16x32_bf16(a, b, c, 0, 0, 0)

// async global->LDS, 16B per lane. LDS dest is wave-uniform base + lane*16.
__device__ __forceinline__ void gl_lds16(const short* g, short* l) {
  __builtin_amdgcn_global_load_lds(
      (const __attribute__((address_space(1))) unsigned int*)(g),
      (__attribute__((address_space(3))) unsigned int*)(l), 16, 0, 0);
}

// ---------- weight convert + transpose: out[n*K + k] = bf16(in[k*N + n]) ----------
__global__ __launch_bounds__(256) void cvt_t(const float* __restrict__ in,
                                             short* __restrict__ out,
                                             int K, int N) {
  __shared__ float tile[32][33];
  int k0 = blockIdx.x * 32, n0 = blockIdx.y * 32;
  int tx = threadIdx.x & 31, ty = threadIdx.x >> 5;
  #pragma unroll
  for (int r = ty; r < 32; r += 8)
    tile[r][tx] = in[(size_t)(k0 + r) * N + n0 + tx];
  __syncthreads();
  #pragma unroll
  for (int r = ty; r < 32; r += 8)
    out[(size_t)(n0 + r) * K + k0 + tx] = f2bf(tile[tx][r]);
}

// ---------- LayerNorm rows of 768: f32 in -> bf16 out (one wave per row) ----------
__global__ __launch_bounds__(256) void ln_rows(const float* __restrict__ x,
                                               const float* __restrict__ g,
                                               const float* __restrict__ b,
                                               short* __restrict__ out) {
  int lane = threadIdx.x & 63, wid = threadIdx.x >> 6;
  int row = blockIdx.x * 4 + wid;
  const float* xr = x + (size_t)row * Dd;
  float v[12];
  float s = 0.f, ss = 0.f;
  #pragma unroll
  for (int c = 0; c < 3; c++) {
    float4 t = *(const float4*)&xr[c * 256 + lane * 4];
    v[c * 4 + 0] = t.x; v[c * 4 + 1] = t.y; v[c * 4 + 2] = t.z; v[c * 4 + 3] = t.w;
    s  += t.x + t.y + t.z + t.w;
    ss += t.x * t.x + t.y * t.y + t.z * t.z + t.w * t.w;
  }
  #pragma unroll
  for (int off = 1; off < 64; off <<= 1) {
    s += __shfl_xor(s, off); ss += __shfl_xor(ss, off);
  }
  float mu   = s * (1.f / Dd);
  float var  = ss * (1.f / Dd) - mu * mu;
  float rstd = rsqrtf(var + 1e-5f);
  #pragma unroll
  for (int c = 0; c < 3; c++) {
    bf16x4 o;
    #pragma unroll
    for (int j = 0; j < 4; j++) {
      int d = c * 256 + lane * 4 + j;
      o[j] = f2bf((v[c * 4 + j] - mu) * rstd * g[d] + b[d]);
    }
    *(bf16x4*)&out[(size_t)row * Dd + c * 256 + lane * 4] = o;
  }
}

// ---------- GEMM: C[M,N] = A[M,K](bf16) * Bt[N,K]^T(bf16) + bias ----------
template <int EPI, int N>
__global__ __launch_bounds__(256) void gemm_bt(const short* __restrict__ A,
                                               const short* __restrict__ Bt,
                                               const float* __restrict__ bias,
                                               const float* __restrict__ add,
                                               void* __restrict__ outp,
                                               int K) {
  __shared__ short S[17408];
  short* As0 = S;
  short* As1 = S + 4096;
  short* Bs0 = S + 8192;
  short* Bs1 = S + 12288;

  int nbx = gridDim.x;
  int flat = blockIdx.y * nbx + blockIdx.x;
  int cpx = (nbx * gridDim.y) >> 3;
  int swz = (flat & 7) * cpx + (flat >> 3);
  int m0 = (swz % nbx) * 128, n0 = (swz / nbx) * 128;

  int tid = threadIdx.x;
  int lane = tid & 63, wid = tid >> 6;
  int wm = wid >> 1, wn = wid & 1;
  int l15 = lane & 15, lg = lane >> 4;

  int jr = tid >> 2, jc = (tid & 3) << 3;
  int ldsb = wid << 9;

  auto stage = [&](short* Ad, short* Bd, int k0) {
    gl_lds16(&A[(size_t)(m0 + jr) * K + k0 + jc],       Ad + ldsb);
    gl_lds16(&A[(size_t)(m0 + 64 + jr) * K + k0 + jc],  Ad + 2048 + ldsb);
    gl_lds16(&Bt[(size_t)(n0 + jr) * K + k0 + jc],      Bd + ldsb);
    gl_lds16(&Bt[(size_t)(n0 + 64 + jr) * K + k0 + jc], Bd + 2048 + ldsb);
  };

  f32x4 acc[4][4] = {};
  stage(As0, Bs0, 0);
  int nk = K >> 5;
  for (int t = 0; t < nk; ++t) {
    short* Ab = (t & 1) ? As1 : As0;
    short* Bb = (t & 1) ? Bs1 : Bs0;
    if (t + 1 < nk) {
      stage((t & 1) ? As0 : As1, (t & 1) ? Bs0 : Bs1, (t + 1) << 5);
      asm volatile("s_waitcnt vmcnt(4)" ::: "memory");
    } else {
      asm volatile("s_waitcnt vmcnt(0)" ::: "memory");
    }
    __syncthreads();
    bf16x8 af[4], bfr[4];
    #pragma unroll
    for (int i = 0; i < 4; i++) af[i]  = *(bf16x8*)&Ab[(wm * 64 + i * 16 + l15) * 32 + lg * 8];
    #pragma unroll
    for (int j = 0; j < 4; j++) bfr[j] = *(bf16x8*)&Bb[(wn * 64 + j * 16 + l15) * 32 + lg * 8];
    #pragma unroll
    for (int i = 0; i < 4; i++)
      #pragma unroll
      for (int j = 0; j < 4; j++)
        acc[i][j] = MFMA16(af[i], bfr[j], acc[i][j]);
    __syncthreads();
  }

  if (EPI == 0 || EPI == 2) {
    short (*Cl)[136] = (short (*)[136])S;
    #pragma unroll
    for (int i = 0; i < 4; i++)
      #pragma unroll
      for (int j = 0; j < 4; j++)
        #pragma unroll
        for (int r = 0; r < 4; r++) {
          int row = wm * 64 + i * 16 + lg * 4 + r;
          int col = wn * 64 + j * 16 + l15;
          float vv = acc[i][j][r] + bias[n0 + col];
          if (EPI == 2) vv = gelu_exact(vv);
          int ch = col >> 3, co = col & 7;
          Cl[row][((ch ^ (row & 7)) << 3) | co] = f2bf(vv);
        }
    __syncthreads();
    int row = tid >> 1;
    int cb = (tid & 1) * 8;
    #pragma unroll
    for (int c = 0; c < 8; c++) {
      int ch = cb + c;
      bf16x8 v8 = *(bf16x8*)&Cl[row][(ch ^ (row & 7)) << 3];
      *(bf16x8*)&((short*)outp)[(size_t)(m0 + row) * N + n0 + (ch << 3)] = v8;
    }
  } else {
    #pragma unroll
    for (int i = 0; i < 4; i++)
      #pragma unroll
      for (int j = 0; j < 4; j++)
        #pragma unroll
        for (int r = 0; r < 4; r++) {
          int m = m0 + wm * 64 + i * 16 + lg * 4 + r;
          int n = n0 + wn * 64 + j * 16 + l15;
          float vv = acc[i][j][r] + bias[n];
          size_t idx = (size_t)m * N + n;
          ((float*)outp)[idx] = vv + add[idx];
        }
  }
}

// ---------- V transpose: Vt[bh][d][t] = V[b,t,h,d] ----------
__global__ __launch_bounds__(256) void vtr(const short* __restrict__ qkv,
                                           short* __restrict__ Vt) {
  __shared__ short Ts[64][72];
  int bh = blockIdx.x, t0 = blockIdx.y * 64;
  int b = bh / Hh, h = bh % Hh;
  int tid = threadIdx.x;
  int r = tid >> 2, dc = (tid & 3) * 16;
  const short* vp = qkv + (size_t)b * Tt * 2304 + (size_t)(t0 + r) * 2304 + 1536 + h * 64 + dc;
  bf16x8 v0 = *(const bf16x8*)vp;
  bf16x8 v1 = *(const bf16x8*)(vp + 8);
  *(bf16x8*)&Ts[r][dc] = v0;
  *(bf16x8*)&Ts[r][dc + 8] = v1;
  __syncthreads();
  int d = tid >> 2, tc = (tid & 3) * 16;
  bf16x8 o0, o1;
  #pragma unroll
  for (int j = 0; j < 8; j++) { o0[j] = Ts[tc + j][d]; o1[j] = Ts[tc + 8 + j][d]; }
  short* op = Vt + ((size_t)bh * 64 + d) * Tt + t0 + tc;
  *(bf16x8*)op = o0;
  *(bf16x8*)(op + 8) = o1;
}

// ---------- attw upper-triangle zero fill ----------
__global__ __launch_bounds__(256) void attn_zero(float* __restrict__ attw) {
  int flat = blockIdx.y * 16 + blockIdx.x;
  int xcd = flat & 7, rr0 = flat >> 3;
  int bh = xcd * 12 + (rr0 >> 4);
  int qtile = rr0 & 15;                 // low qtile = most zero tiles, first
  int tid = threadIdx.x;
  f32x4 z = {0.f, 0.f, 0.f, 0.f};
  for (int kt = qtile + 1; kt < 16; ++kt) {
    #pragma unroll
    for (int p = 0; p < 4; ++p) {
      int row = (tid >> 4) + p * 16;
      *(f32x4*)&attw[((size_t)bh * Tt + qtile * 64 + row) * Tt + kt * 64 + (tid & 15) * 4] = z;
    }
  }
}

// ---------- attention pass 1: softmax denominators (no max-sub; scores bounded) ----------
// Swapped S^T = MFMA(K, Q): lane holds fixed q=l15, 16 t-values -> pure per-lane
// accumulate, 2 shuffles at the end. No LDS, K prefetched one tile ahead.
__global__ __launch_bounds__(256) void attn_sums(const short* __restrict__ qkv,
                                                 float* __restrict__ sums) {
  int flat = blockIdx.y * 16 + blockIdx.x;
  int xcd = flat & 7, rr0 = flat >> 3;
  int bh = xcd * 12 + (rr0 >> 4);
  int tile = 15 - (rr0 & 15);           // heavy first
  int q0 = tile * 64;
  int b = bh / Hh, h = bh % Hh;
  int tid = threadIdx.x, lane = tid & 63, wid = tid >> 6;
  int l15 = lane & 15, lg = lane >> 4;
  const short* base = qkv + (size_t)b * Tt * 2304;

  bf16x8 qa[2];
  {
    const short* qp = base + (size_t)(q0 + wid * 16 + l15) * 2304 + h * 64 + lg * 8;
    qa[0] = *(const bf16x8*)qp;
    qa[1] = *(const bf16x8*)(qp + 32);
  }
  const short* kbase = base + 768 + h * 64 + (size_t)l15 * 2304 + lg * 8;
  int q = q0 + wid * 16 + l15;

  bf16x8 kc[8], kn[8];
  #pragma unroll
  for (int nf = 0; nf < 4; nf++) {
    const short* kp = kbase + (size_t)(nf * 16) * 2304;
    kc[2 * nf]     = *(const bf16x8*)kp;
    kc[2 * nf + 1] = *(const bf16x8*)(kp + 32);
  }
  float lsum = 0.f;
  for (int kt = 0; kt <= tile; ++kt) {
    if (kt < tile) {
      #pragma unroll
      for (int nf = 0; nf < 4; nf++) {
        const short* kp = kbase + (size_t)((kt + 1) * 64 + nf * 16) * 2304;
        kn[2 * nf]     = *(const bf16x8*)kp;
        kn[2 * nf + 1] = *(const bf16x8*)(kp + 32);
      }
    }
    f32x4 acc[4] = {};
    #pragma unroll
    for (int nf = 0; nf < 4; nf++) {
      acc[nf] = MFMA16(kc[2 * nf],     qa[0], acc[nf]);   // A=K, B=Q -> S^T
      acc[nf] = MFMA16(kc[2 * nf + 1], qa[1], acc[nf]);
    }
    #pragma unroll
    for (int nf = 0; nf < 4; nf++)
      #pragma unroll
      for (int r = 0; r < 4; r++) {
        int t = kt * 64 + nf * 16 + lg * 4 + r;
        lsum += (t <= q) ? __expf(acc[nf][r] * 0.125f) : 0.f;
      }
    #pragma unroll
    for (int i = 0; i < 8; i++) kc[i] = kn[i];
  }
  lsum += __shfl_xor(lsum, 16);
  lsum += __shfl_xor(lsum, 32);
  if (lane < 16) sums[(size_t)bh * Tt + q0 + wid * 16 + lane] = lsum;
}

// ---------- attention pass 2: P-write + PV, barrier-free ----------
// S^T orientation: attw stored f32x4 direct from registers (4 consecutive t per
// lane). PV uses global Vt (A-operand, contiguous) and a wave-local bf16 LDS
// transpose for P (lgkmcnt-only sync). No __syncthreads anywhere.
__global__ __launch_bounds__(256) void attn_main(const short* __restrict__ qkv,
                                                 const short* __restrict__ Vt,
                                                 const float* __restrict__ sums,
                                                 float* __restrict__ attw,
                                                 short* __restrict__ ctx) {
  __shared__ short Plb[4][16][72];      // per-wave P (bf16), 9.2 KB
  int flat = blockIdx.y * 16 + blockIdx.x;
  int xcd = flat & 7, rr0 = flat >> 3;
  int bh = xcd * 12 + (rr0 >> 4);
  int tile = 15 - (rr0 & 15);           // heavy first
  int q0 = tile * 64;
  int b = bh / Hh, h = bh % Hh;
  int tid = threadIdx.x, lane = tid & 63, wid = tid >> 6;
  int l15 = lane & 15, lg = lane >> 4;
  const short* base = qkv + (size_t)b * Tt * 2304;

  bf16x8 qa[2];
  {
    const short* qp = base + (size_t)(q0 + wid * 16 + l15) * 2304 + h * 64 + lg * 8;
    qa[0] = *(const bf16x8*)qp;
    qa[1] = *(const bf16x8*)(qp + 32);
  }
  int q = q0 + wid * 16 + l15;
  float rl = 1.f / sums[(size_t)bh * Tt + q];
  const short* kbase = base + 768 + h * 64 + (size_t)l15 * 2304 + lg * 8;
  const short* vtb = Vt + ((size_t)bh * 64 + l15) * Tt + lg * 8;
  float* awrow = attw + ((size_t)bh * Tt + q) * Tt;

  f32x4 oacc[4] = {};
  for (int kt = 0; kt <= tile; ++kt) {
    bf16x8 kc[8], va[8];
    #pragma unroll
    for (int nf = 0; nf < 4; nf++) {
      const short* kp = kbase + (size_t)(kt * 64 + nf * 16) * 2304;
      kc[2 * nf]     = *(const bf16x8*)kp;
      kc[2 * nf + 1] = *(const bf16x8*)(kp + 32);
      const short* vp = vtb + (size_t)nf * 16 * Tt + kt * 64;
      va[2 * nf]     = *(const bf16x8*)vp;
      va[2 * nf + 1] = *(const bf16x8*)(vp + 32);
    }
    f32x4 acc[4] = {};
    #pragma unroll
    for (int nf = 0; nf < 4; nf++) {
      acc[nf] = MFMA16(kc[2 * nf],     qa[0], acc[nf]);   // S^T
      acc[nf] = MFMA16(kc[2 * nf + 1], qa[1], acc[nf]);
    }
    #pragma unroll
    for (int nf = 0; nf < 4; nf++) {
      f32x4 p4;
      #pragma unroll
      for (int r = 0; r < 4; r++) {
        int t = kt * 64 + nf * 16 + lg * 4 + r;
        p4[r] = (t <= q) ? __expf(acc[nf][r] * 0.125f) * rl : 0.f;
      }
      *(f32x4*)&awrow[kt * 64 + nf * 16 + lg * 4] = p4;
      unsigned lo = (unsigned short)f2bf(p4[0]) | ((unsigned)(unsigned short)f2bf(p4[1]) << 16);
      unsigned hi = (unsigned short)f2bf(p4[2]) | ((unsigned)(unsigned short)f2bf(p4[3]) << 16);
      *(unsigned*)&Plb[wid][l15][nf * 16 + lg * 4]     = lo;
      *(unsigned*)&Plb[wid][l15][nf * 16 + lg * 4 + 2] = hi;
    }
    asm volatile("s_waitcnt lgkmcnt(0)" ::: "memory");
    __builtin_amdgcn_sched_barrier(0);
    bf16x8 pb0 = *(bf16x8*)&Plb[wid][l15][lg * 8];
    bf16x8 pb1 = *(bf16x8*)&Plb[wid][l15][lg * 8 + 32];
    __builtin_amdgcn_s_setprio(1);
    #pragma unroll
    for (int nf = 0; nf < 4; nf++) {
      oacc[nf] = MFMA16(va[2 * nf],     pb0, oacc[nf]);   // O^T = V^T * P^T
      oacc[nf] = MFMA16(va[2 * nf + 1], pb1, oacc[nf]);
    }
    __builtin_amdgcn_s_setprio(0);
  }
  #pragma unroll
  for (int nf = 0; nf < 4; nf++) {
    bf16x4 o4;
    #pragma unroll
    for (int r = 0; r < 4; r++) o4[r] = f2bf(oacc[nf][r]);
    *(bf16x4*)&ctx[((size_t)b * Tt + q) * Dd + h * 64 + nf * 16 + lg * 4] = o4;
  }
}

}  // namespace

extern "C" void kernel_launch(void* const* d_in, const int* in_sizes, int n_in,
                              void* d_out, int out_size, void* d_ws, size_t ws_size,
                              hipStream_t stream) {
  const float* x     = (const float*)d_in[0];
  const float* ln1g  = (const float*)d_in[1];
  const float* ln1b  = (const float*)d_in[2];
  const float* w_qkv = (const float*)d_in[3];
  const float* b_qkv = (const float*)d_in[4];
  const float* w_out = (const float*)d_in[5];
  const float* b_out = (const float*)d_in[6];
  const float* ln2g  = (const float*)d_in[7];
  const float* ln2b  = (const float*)d_in[8];
  const float* w_fc1 = (const float*)d_in[9];
  const float* b_fc1 = (const float*)d_in[10];
  const float* w_fc2 = (const float*)d_in[11];
  const float* b_fc2 = (const float*)d_in[12];

  char* ws = (char*)d_ws;
  size_t o = 0;
  short* wqkvT = (short*)(ws + o); o += (size_t)2304 * 768 * 2;
  short* woutT = (short*)(ws + o); o += (size_t)768 * 768 * 2;
  short* wfc1T = (short*)(ws + o); o += (size_t)3072 * 768 * 2;
  short* wfc2T = (short*)(ws + o); o += (size_t)768 * 3072 * 2;
  short* h     = (short*)(ws + o); o += (size_t)BT * Dd * 2;
  short* qkv   = (short*)(ws + o); o += (size_t)BT * 2304 * 2;
  float* y1    = (float*)(ws + o); o += (size_t)BT * Dd * 4;
  short* h2    = (short*)(ws + o); o += (size_t)BT * Dd * 2;
  short* vt    = (short*)(ws + o); o += (size_t)96 * 64 * Tt * 2;   // 12.58 MB
  float* sums  = (float*)(ws + o); o += (size_t)96 * Tt * 4;        // 393 KB
  short* ctx  = h;     // reuse: h dead after QKV GEMM
  short* gbuf = h;     // reuse: h+qkv regions for GELU output (BT*DFF*2 bytes)

  float* out_x = (float*)d_out;
  float* attw  = out_x + (size_t)BT * Dd;

  cvt_t<<<dim3(768 / 32, 2304 / 32), 256, 0, stream>>>(w_qkv, wqkvT, 768, 2304);
  cvt_t<<<dim3(768 / 32, 768 / 32),  256, 0, stream>>>(w_out, woutT, 768, 768);
  cvt_t<<<dim3(768 / 32, 3072 / 32), 256, 0, stream>>>(w_fc1, wfc1T, 768, 3072);
  cvt_t<<<dim3(3072 / 32, 768 / 32), 256, 0, stream>>>(w_fc2, wfc2T, 3072, 768);

  ln_rows<<<BT / 4, 256, 0, stream>>>(x, ln1g, ln1b, h);
  gemm_bt<0, 2304><<<dim3(BT / 128, 2304 / 128), 256, 0, stream>>>(h, wqkvT, b_qkv, nullptr, qkv, 768);
  vtr<<<dim3(96, 16), 256, 0, stream>>>(qkv, vt);
  attn_zero<<<dim3(16, 96), 256, 0, stream>>>(attw);
  attn_sums<<<dim3(16, 96), 256, 0, stream>>>(qkv, sums);
  attn_main<<<dim3(16, 96), 256, 0, stream>>>(qkv, vt, sums, attw, ctx);
  gemm_bt<1, 768><<<dim3(BT / 128, 768 / 128), 256, 0, stream>>>(ctx, woutT, b_out, x, y1, 768);
  ln_rows<<<BT / 4, 256, 0, stream>>>(y1, ln2g, ln2b, h2);
  gemm_bt<2, 3072><<<dim3(BT / 128, 3072 / 128), 256, 0, stream>>>(h2, wfc1T, b_fc1, nullptr, gbuf, 768);
  gemm_bt<3, 768><<<dim3(BT / 128, 768 / 128), 256, 0, stream>>>(gbuf, wfc2T, b_fc2, y1, out_x, 3072);
}

// Round 6
// 441.652 us; speedup vs baseline: 1.2946x; 1.2946x over previous
//
#include <hip/hip_runtime.h>
#include <cstdint>
#include <cstddef>

namespace {

constexpr int Bb  = 8;
constexpr int Tt  = 1024;
constexpr int Dd  = 768;
constexpr int Hh  = 12;
constexpr int DFF = 3072;
constexpr int BT  = Bb * Tt;

typedef __attribute__((ext_vector_type(8))) short bf16x8;
typedef __attribute__((ext_vector_type(4))) short bf16x4;
typedef __attribute__((ext_vector_type(4))) float f32x4;

__device__ __forceinline__ short f2bf(float f) {
  union { float f; unsigned u; } v; v.f = f;
  unsigned r = v.u + 0x7fffu + ((v.u >> 16) & 1u);   // RNE
  return (short)(r >> 16);
}
__device__ __forceinline__ float gelu_exact(float v) {
  return 0.5f * v * (1.0f + erff(v * 0.70710678118654752f));
}

#define MFMA16(a, b, c) __builtin_amdgcn_mfma_f32_16x16x32_bf16(a, b, c, 0, 0, 0)

// async global->LDS, 16B per lane. LDS dest is wave-uniform base + lane*16.
__device__ __forceinline__ void gl_lds16(const short* g, short* l) {
  __builtin_amdgcn_global_load_lds(
      (const __attribute__((address_space(1))) unsigned int*)(g),
      (__attribute__((address_space(3))) unsigned int*)(l), 16, 0, 0);
}

// ---------- weight convert + transpose: out[n*K + k] = bf16(in[k*N + n]) ----------
__global__ __launch_bounds__(256) void cvt_t(const float* __restrict__ in,
                                             short* __restrict__ out,
                                             int K, int N) {
  __shared__ float tile[32][33];
  int k0 = blockIdx.x * 32, n0 = blockIdx.y * 32;
  int tx = threadIdx.x & 31, ty = threadIdx.x >> 5;
  #pragma unroll
  for (int r = ty; r < 32; r += 8)
    tile[r][tx] = in[(size_t)(k0 + r) * N + n0 + tx];
  __syncthreads();
  #pragma unroll
  for (int r = ty; r < 32; r += 8)
    out[(size_t)(n0 + r) * K + k0 + tx] = f2bf(tile[tx][r]);
}

// ---------- LayerNorm rows of 768: f32 in -> bf16 out (one wave per row) ----------
__global__ __launch_bounds__(256) void ln_rows(const float* __restrict__ x,
                                               const float* __restrict__ g,
                                               const float* __restrict__ b,
                                               short* __restrict__ out) {
  int lane = threadIdx.x & 63, wid = threadIdx.x >> 6;
  int row = blockIdx.x * 4 + wid;
  const float* xr = x + (size_t)row * Dd;
  float v[12];
  float s = 0.f, ss = 0.f;
  #pragma unroll
  for (int c = 0; c < 3; c++) {
    float4 t = *(const float4*)&xr[c * 256 + lane * 4];
    v[c * 4 + 0] = t.x; v[c * 4 + 1] = t.y; v[c * 4 + 2] = t.z; v[c * 4 + 3] = t.w;
    s  += t.x + t.y + t.z + t.w;
    ss += t.x * t.x + t.y * t.y + t.z * t.z + t.w * t.w;
  }
  #pragma unroll
  for (int off = 1; off < 64; off <<= 1) {
    s += __shfl_xor(s, off); ss += __shfl_xor(ss, off);
  }
  float mu   = s * (1.f / Dd);
  float var  = ss * (1.f / Dd) - mu * mu;
  float rstd = rsqrtf(var + 1e-5f);
  #pragma unroll
  for (int c = 0; c < 3; c++) {
    bf16x4 o;
    #pragma unroll
    for (int j = 0; j < 4; j++) {
      int d = c * 256 + lane * 4 + j;
      o[j] = f2bf((v[c * 4 + j] - mu) * rstd * g[d] + b[d]);
    }
    *(bf16x4*)&out[(size_t)row * Dd + c * 256 + lane * 4] = o;
  }
}

// ---------- GEMM: C[M,N] = A[M,K](bf16) * Bt[N,K]^T(bf16) + bias ----------
// (identical to R3/R4; EPI 3 output is streaming -> nontemporal)
template <int EPI, int N>
__global__ __launch_bounds__(256) void gemm_bt(const short* __restrict__ A,
                                               const short* __restrict__ Bt,
                                               const float* __restrict__ bias,
                                               const float* __restrict__ add,
                                               void* __restrict__ outp,
                                               int K) {
  __shared__ short S[17408];
  short* As0 = S;
  short* As1 = S + 4096;
  short* Bs0 = S + 8192;
  short* Bs1 = S + 12288;

  int nbx = gridDim.x;
  int flat = blockIdx.y * nbx + blockIdx.x;
  int cpx = (nbx * gridDim.y) >> 3;
  int swz = (flat & 7) * cpx + (flat >> 3);
  int m0 = (swz % nbx) * 128, n0 = (swz / nbx) * 128;

  int tid = threadIdx.x;
  int lane = tid & 63, wid = tid >> 6;
  int wm = wid >> 1, wn = wid & 1;
  int l15 = lane & 15, lg = lane >> 4;

  int jr = tid >> 2, jc = (tid & 3) << 3;
  int ldsb = wid << 9;

  auto stage = [&](short* Ad, short* Bd, int k0) {
    gl_lds16(&A[(size_t)(m0 + jr) * K + k0 + jc],       Ad + ldsb);
    gl_lds16(&A[(size_t)(m0 + 64 + jr) * K + k0 + jc],  Ad + 2048 + ldsb);
    gl_lds16(&Bt[(size_t)(n0 + jr) * K + k0 + jc],      Bd + ldsb);
    gl_lds16(&Bt[(size_t)(n0 + 64 + jr) * K + k0 + jc], Bd + 2048 + ldsb);
  };

  f32x4 acc[4][4] = {};
  stage(As0, Bs0, 0);
  int nk = K >> 5;
  for (int t = 0; t < nk; ++t) {
    short* Ab = (t & 1) ? As1 : As0;
    short* Bb = (t & 1) ? Bs1 : Bs0;
    if (t + 1 < nk) {
      stage((t & 1) ? As0 : As1, (t & 1) ? Bs0 : Bs1, (t + 1) << 5);
      asm volatile("s_waitcnt vmcnt(4)" ::: "memory");
    } else {
      asm volatile("s_waitcnt vmcnt(0)" ::: "memory");
    }
    __syncthreads();
    bf16x8 af[4], bfr[4];
    #pragma unroll
    for (int i = 0; i < 4; i++) af[i]  = *(bf16x8*)&Ab[(wm * 64 + i * 16 + l15) * 32 + lg * 8];
    #pragma unroll
    for (int j = 0; j < 4; j++) bfr[j] = *(bf16x8*)&Bb[(wn * 64 + j * 16 + l15) * 32 + lg * 8];
    #pragma unroll
    for (int i = 0; i < 4; i++)
      #pragma unroll
      for (int j = 0; j < 4; j++)
        acc[i][j] = MFMA16(af[i], bfr[j], acc[i][j]);
    __syncthreads();
  }

  if (EPI == 0 || EPI == 2) {
    short (*Cl)[136] = (short (*)[136])S;
    #pragma unroll
    for (int i = 0; i < 4; i++)
      #pragma unroll
      for (int j = 0; j < 4; j++)
        #pragma unroll
        for (int r = 0; r < 4; r++) {
          int row = wm * 64 + i * 16 + lg * 4 + r;
          int col = wn * 64 + j * 16 + l15;
          float vv = acc[i][j][r] + bias[n0 + col];
          if (EPI == 2) vv = gelu_exact(vv);
          int ch = col >> 3, co = col & 7;
          Cl[row][((ch ^ (row & 7)) << 3) | co] = f2bf(vv);
        }
    __syncthreads();
    int row = tid >> 1;
    int cb = (tid & 1) * 8;
    #pragma unroll
    for (int c = 0; c < 8; c++) {
      int ch = cb + c;
      bf16x8 v8 = *(bf16x8*)&Cl[row][(ch ^ (row & 7)) << 3];
      *(bf16x8*)&((short*)outp)[(size_t)(m0 + row) * N + n0 + (ch << 3)] = v8;
    }
  } else {
    #pragma unroll
    for (int i = 0; i < 4; i++)
      #pragma unroll
      for (int j = 0; j < 4; j++)
        #pragma unroll
        for (int r = 0; r < 4; r++) {
          int m = m0 + wm * 64 + i * 16 + lg * 4 + r;
          int n = n0 + wn * 64 + j * 16 + l15;
          float vv = acc[i][j][r] + bias[n];
          size_t idx = (size_t)m * N + n;
          float ov = vv + add[idx];
          if (EPI == 3) __builtin_nontemporal_store(ov, &((float*)outp)[idx]);
          else          ((float*)outp)[idx] = ov;
        }
  }
}

// ---------- fused causal attention (R2 structure; no-max softmax; nt attw stores) ----------
// grid (16, 96): all 16 q-tiles of one (b,h) on one XCD, heavy tiles first (LPT).
// 4 waves; wave w owns q-rows [q0+16w, q0+16w+16). Pass 1: per-lane sumexp only.
// Pass 2: recompute scores, LDS-stage P (f32), 256B-coalesced nontemporal attw
// stores, PV via LDS-transposed V.
__global__ __launch_bounds__(256) void attn_fused(const short* __restrict__ qkv,
                                                  float* __restrict__ attw,
                                                  short* __restrict__ ctx) {
  __shared__ short Vt[64][72];       // V^T tile (9.2 KB)
  __shared__ float Pf[4][16][68];    // per-wave P f32 staging (17.4 KB)
  int flat = blockIdx.y * 16 + blockIdx.x;
  int xcd = flat & 7, rr0 = flat >> 3;
  int bh   = xcd * 12 + (rr0 >> 4);
  int tile = 15 - (rr0 & 15);        // heavy first (LPT)
  int q0 = tile * 64;
  int b = bh / Hh, h = bh % Hh;
  int tid = threadIdx.x, lane = tid & 63, wid = tid >> 6;
  int l15 = lane & 15, lg = lane >> 4;
  const short* base = qkv + (size_t)b * Tt * 2304;

  bf16x8 qa[2];
  {
    const short* qp = base + (size_t)(q0 + wid * 16 + l15) * 2304 + h * 64 + lg * 8;
    qa[0] = *(const bf16x8*)qp;
    qa[1] = *(const bf16x8*)(qp + 32);
  }

  // ---- pass 1: per-lane sumexp only (no max-sub: |s| bounded, exp safe) ----
  float l[4] = {0.f, 0.f, 0.f, 0.f};
  for (int kt = 0; kt <= tile; ++kt) {
    f32x4 acc[4] = {};
    #pragma unroll
    for (int nf = 0; nf < 4; ++nf) {
      const short* kp = base + (size_t)(kt * 64 + nf * 16 + l15) * 2304 + 768 + h * 64 + lg * 8;
      bf16x8 k0 = *(const bf16x8*)kp;
      bf16x8 k1 = *(const bf16x8*)(kp + 32);
      acc[nf] = MFMA16(qa[0], k0, acc[nf]);
      acc[nf] = MFMA16(qa[1], k1, acc[nf]);
    }
    #pragma unroll
    for (int r = 0; r < 4; r++) {
      int qg = q0 + wid * 16 + lg * 4 + r;
      #pragma unroll
      for (int nf = 0; nf < 4; nf++) {
        int kg = kt * 64 + nf * 16 + l15;
        l[r] += (kg <= qg) ? __expf(acc[nf][r] * 0.125f) : 0.f;
      }
    }
  }
  float rl[4];
  #pragma unroll
  for (int r = 0; r < 4; r++) {
    float s = l[r];
    #pragma unroll
    for (int off = 1; off < 16; off <<= 1) s += __shfl_xor(s, off);
    rl[r] = 1.f / s;
  }

  // ---- pass 2: recompute scores, write attw (coalesced nt), accumulate PV ----
  f32x4 oacc[4] = {};
  for (int kt = 0; kt <= tile; ++kt) {
    __syncthreads();                   // prior Vt reads complete
    {
      int t = tid & 63, dv = (tid >> 6) * 16;
      const short* vp = base + (size_t)(kt * 64 + t) * 2304 + 1536 + h * 64 + dv;
      bf16x8 v0 = *(const bf16x8*)vp;
      bf16x8 v1 = *(const bf16x8*)(vp + 8);
      #pragma unroll
      for (int j = 0; j < 8; j++) Vt[dv + j][t] = v0[j];
      #pragma unroll
      for (int j = 0; j < 8; j++) Vt[dv + 8 + j][t] = v1[j];
    }
    __syncthreads();

    f32x4 acc[4] = {};
    #pragma unroll
    for (int nf = 0; nf < 4; nf++) {
      const short* kp = base + (size_t)(kt * 64 + nf * 16 + l15) * 2304 + 768 + h * 64 + lg * 8;
      bf16x8 k0 = *(const bf16x8*)kp;
      bf16x8 k1 = *(const bf16x8*)(kp + 32);
      acc[nf] = MFMA16(qa[0], k0, acc[nf]);
      acc[nf] = MFMA16(qa[1], k1, acc[nf]);
    }
    #pragma unroll
    for (int nf = 0; nf < 4; nf++) {
      #pragma unroll
      for (int r = 0; r < 4; r++) {
        int qg = q0 + wid * 16 + lg * 4 + r;
        int kg = kt * 64 + nf * 16 + l15;
        float p = (kg <= qg) ? __expf(acc[nf][r] * 0.125f) * rl[r] : 0.f;
        Pf[wid][lg * 4 + r][nf * 16 + l15] = p;
      }
    }
    asm volatile("s_waitcnt lgkmcnt(0)" ::: "memory");
    __builtin_amdgcn_sched_barrier(0);
    // coalesced attw write: f32x4, 256B segments per row, nontemporal
    #pragma unroll
    for (int it = 0; it < 4; ++it) {
      int pr = it * 4 + lg;
      f32x4 pv = *(f32x4*)&Pf[wid][pr][l15 * 4];
      __builtin_nontemporal_store(
          pv, (f32x4*)&attw[((size_t)bh * Tt + q0 + wid * 16 + pr) * Tt + kt * 64 + l15 * 4]);
    }
    f32x4 pf0 = *(f32x4*)&Pf[wid][l15][lg * 8];
    f32x4 pf1 = *(f32x4*)&Pf[wid][l15][lg * 8 + 4];
    f32x4 pf2 = *(f32x4*)&Pf[wid][l15][lg * 8 + 32];
    f32x4 pf3 = *(f32x4*)&Pf[wid][l15][lg * 8 + 36];
    bf16x8 pa0, pa1;
    #pragma unroll
    for (int j = 0; j < 4; j++) {
      pa0[j] = f2bf(pf0[j]); pa0[4 + j] = f2bf(pf1[j]);
      pa1[j] = f2bf(pf2[j]); pa1[4 + j] = f2bf(pf3[j]);
    }
    #pragma unroll
    for (int nf = 0; nf < 4; nf++) {
      bf16x8 vb0 = *(bf16x8*)&Vt[nf * 16 + l15][lg * 8];
      bf16x8 vb1 = *(bf16x8*)&Vt[nf * 16 + l15][lg * 8 + 32];
      oacc[nf] = MFMA16(pa0, vb0, oacc[nf]);
      oacc[nf] = MFMA16(pa1, vb1, oacc[nf]);
    }
  }
  // strictly-upper zero tiles (nontemporal)
  f32x4 z = {0.f, 0.f, 0.f, 0.f};
  for (int kt = tile + 1; kt < 16; ++kt) {
    #pragma unroll
    for (int it = 0; it < 4; ++it) {
      int pr = it * 4 + lg;
      __builtin_nontemporal_store(
          z, (f32x4*)&attw[((size_t)bh * Tt + q0 + wid * 16 + pr) * Tt + kt * 64 + l15 * 4]);
    }
  }
  #pragma unroll
  for (int nf = 0; nf < 4; nf++) {
    #pragma unroll
    for (int r = 0; r < 4; r++) {
      int t = q0 + wid * 16 + lg * 4 + r;
      ctx[((size_t)b * Tt + t) * Dd + h * 64 + nf * 16 + l15] = f2bf(oacc[nf][r]);
    }
  }
}

}  // namespace

extern "C" void kernel_launch(void* const* d_in, const int* in_sizes, int n_in,
                              void* d_out, int out_size, void* d_ws, size_t ws_size,
                              hipStream_t stream) {
  const float* x     = (const float*)d_in[0];
  const float* ln1g  = (const float*)d_in[1];
  const float* ln1b  = (const float*)d_in[2];
  const float* w_qkv = (const float*)d_in[3];
  const float* b_qkv = (const float*)d_in[4];
  const float* w_out = (const float*)d_in[5];
  const float* b_out = (const float*)d_in[6];
  const float* ln2g  = (const float*)d_in[7];
  const float* ln2b  = (const float*)d_in[8];
  const float* w_fc1 = (const float*)d_in[9];
  const float* b_fc1 = (const float*)d_in[10];
  const float* w_fc2 = (const float*)d_in[11];
  const float* b_fc2 = (const float*)d_in[12];

  char* ws = (char*)d_ws;
  size_t o = 0;
  short* wqkvT = (short*)(ws + o); o += (size_t)2304 * 768 * 2;
  short* woutT = (short*)(ws + o); o += (size_t)768 * 768 * 2;
  short* wfc1T = (short*)(ws + o); o += (size_t)3072 * 768 * 2;
  short* wfc2T = (short*)(ws + o); o += (size_t)768 * 3072 * 2;
  short* h     = (short*)(ws + o); o += (size_t)BT * Dd * 2;
  short* qkv   = (short*)(ws + o); o += (size_t)BT * 2304 * 2;
  float* y1    = (float*)(ws + o); o += (size_t)BT * Dd * 4;
  short* h2    = (short*)(ws + o); o += (size_t)BT * Dd * 2;
  short* ctx  = h;     // reuse: h dead after QKV GEMM
  short* gbuf = h;     // reuse: h+qkv regions for GELU output (BT*DFF*2 bytes)

  float* out_x = (float*)d_out;
  float* attw  = out_x + (size_t)BT * Dd;

  cvt_t<<<dim3(768 / 32, 2304 / 32), 256, 0, stream>>>(w_qkv, wqkvT, 768, 2304);
  cvt_t<<<dim3(768 / 32, 768 / 32),  256, 0, stream>>>(w_out, woutT, 768, 768);
  cvt_t<<<dim3(768 / 32, 3072 / 32), 256, 0, stream>>>(w_fc1, wfc1T, 768, 3072);
  cvt_t<<<dim3(3072 / 32, 768 / 32), 256, 0, stream>>>(w_fc2, wfc2T, 3072, 768);

  ln_rows<<<BT / 4, 256, 0, stream>>>(x, ln1g, ln1b, h);
  gemm_bt<0, 2304><<<dim3(BT / 128, 2304 / 128), 256, 0, stream>>>(h, wqkvT, b_qkv, nullptr, qkv, 768);
  attn_fused<<<dim3(16, 96), 256, 0, stream>>>(qkv, attw, ctx);
  gemm_bt<1, 768><<<dim3(BT / 128, 768 / 128), 256, 0, stream>>>(ctx, woutT, b_out, x, y1, 768);
  ln_rows<<<BT / 4, 256, 0, stream>>>(y1, ln2g, ln2b, h2);
  gemm_bt<2, 3072><<<dim3(BT / 128, 3072 / 128), 256, 0, stream>>>(h2, wfc1T, b_fc1, nullptr, gbuf, 768);
  gemm_bt<3, 768><<<dim3(BT / 128, 768 / 128), 256, 0, stream>>>(gbuf, wfc2T, b_fc2, y1, out_x, 3072);
}